// Round 7
// baseline (140.647 us; speedup 1.0000x reference)
//
#include <hip/hip_runtime.h>
#include <hip/hip_bf16.h>
#include <stdint.h>

#define N2 8192
#define D 256
#define DB 512          // bytes per bf16 row
#define TILE 256        // block tile: 256 rows x 256 cols
#define NRB (N2 / TILE)                 // 32
#define NTILES (NRB * (NRB + 1) / 2)    // 528 upper-triangle tiles
#define CHUNK 32
#define NCHUNK (TILE / CHUNK)           // 8
#define SWZ(r, b) ((b) ^ (((r) & 7) << 4))
// rows pre-scaled by s, s^2 = 2*log2(e): MFMA acc is already exp2-domain
#define PRESCALE 1.6986436f
#define INV_S2   0.34657359f   // ln2/2: acc -> raw dot

using short8 = __attribute__((ext_vector_type(8))) short;
using f32x4  = __attribute__((ext_vector_type(4))) float;

typedef __attribute__((address_space(1))) const char gchar_t;
typedef __attribute__((address_space(3))) char       lchar_t;

__device__ inline float fast_exp2(float x) {
    float r;
    asm volatile("v_exp_f32 %0, %1\n\ts_nop 0" : "=v"(r) : "v"(x));
    return r;
}

__device__ inline unsigned short f2bf(float x) {
    union { float f; uint32_t u; } a; a.f = x;
    uint32_t r = (a.u + 0x7fff + ((a.u >> 16) & 1)) >> 16;  // RNE
    return (unsigned short)r;
}

// ---------------- kernel 1: interleave + L2-normalize + scale + bf16 --------
__global__ void knorm(const float* __restrict__ z1, const float* __restrict__ z2,
                      unsigned short* __restrict__ Zb, float* __restrict__ den,
                      int* __restrict__ counter) {
    int tid  = threadIdx.x;
    int lane = tid & 63;
    int w    = tid >> 6;
    int row  = blockIdx.x * 4 + w;          // 0..8191
    const float* src = (row & 1) ? z2 : z1;
    int srow = row >> 1;
    float4 v = reinterpret_cast<const float4*>(src + (size_t)srow * D)[lane];
    float ss = v.x*v.x + v.y*v.y + v.z*v.z + v.w*v.w;
    #pragma unroll
    for (int off = 1; off < 64; off <<= 1) ss += __shfl_xor(ss, off);
    float inv = rsqrtf(ss) * PRESCALE;
    ushort4 o;
    o.x = f2bf(v.x * inv); o.y = f2bf(v.y * inv);
    o.z = f2bf(v.z * inv); o.w = f2bf(v.w * inv);
    *reinterpret_cast<ushort4*>(Zb + (size_t)row * D + lane * 4) = o;

    int gid = blockIdx.x * blockDim.x + tid;
    if (gid < N2) den[gid] = 0.f;
    if (gid == 0) *counter = 0;
}

// ---- kernel 2: upper-triangle tiles; row+col exp-sums; pos; final loss ----
__launch_bounds__(256, 2)
__global__ void kmain(const unsigned short* __restrict__ Zb,
                      float* __restrict__ den, float* __restrict__ pos,
                      int* __restrict__ counter, float* __restrict__ out) {
    __shared__ char tile[2][CHUNK * DB];     // 2 x 16 KB double buffer
    int tid  = threadIdx.x;
    int lane = tid & 63;
    int w    = tid >> 6;                     // 0..3
    int l15 = lane & 15, g = lane >> 4;

    // triangle decode: bid -> (rb, cb), cb >= rb
    int bid = blockIdx.x;
    int rb = 0, cum = 0;
    while (cum + (NRB - rb) <= bid) { cum += NRB - rb; ++rb; }
    int cb = rb + (bid - cum);
    bool isDiag = (rb == cb);
    int Rbase = rb * TILE, Cbase = cb * TILE;
    int Rw = Rbase + w * 64;                 // wave's 64-row base

    const char* Zc = reinterpret_cast<const char*>(Zb);

    // staging: 256 threads stage 32 rows (16 KB) via 4 DMA ops each 2 rows;
    // global source pre-swizzled so linear LDS dest yields swizzled layout.
    int soff[4];
    #pragma unroll
    for (int k = 0; k < 4; ++k) {
        int r = w*8 + k*2 + (lane >> 5);     // local row 0..31
        int y = (lane & 31) * 16;
        soff[k] = r * DB + SWZ(r, y);
    }
    const size_t cbase0 = (size_t)Cbase * DB;

    #define STAGE(bf, coff)                                                          \
        _Pragma("unroll")                                                            \
        for (int k = 0; k < 4; ++k)                                                  \
            __builtin_amdgcn_global_load_lds(                                        \
                (gchar_t*)(Zc + (coff) + soff[k]),                                   \
                (lchar_t*)(&tile[bf][(w*8 + k*2) * DB]), 16, 0, 0);

    STAGE(0, cbase0);                        // prologue: chunk 0 -> buf 0

    // A fragments (compiler may remat; tolerated)
    short8 A[4][8];
    #pragma unroll
    for (int mf = 0; mf < 4; ++mf) {
        const char* rowp = Zc + (size_t)(Rw + mf*16 + l15) * DB + g*16;
        #pragma unroll
        for (int s = 0; s < 8; ++s)
            A[mf][s] = *reinterpret_cast<const short8*>(rowp + s*64);
    }

    float rsum[4][4];
    #pragma unroll
    for (int mf = 0; mf < 4; ++mf)
        #pragma unroll
        for (int r = 0; r < 4; ++r) rsum[mf][r] = 0.f;

    int buf = 0;
    for (int c = 0; c < NCHUNK; ++c) {
        if (c + 1 < NCHUNK) {                // buf^1's readers finished last iter
            STAGE(buf ^ 1, cbase0 + (size_t)(c + 1) * CHUNK * DB);
            asm volatile("s_waitcnt vmcnt(4)" ::: "memory");  // chunk c landed
        } else {
            asm volatile("s_waitcnt vmcnt(0)" ::: "memory");
        }
        __builtin_amdgcn_s_barrier();
        __builtin_amdgcn_sched_barrier(0);

        f32x4 acc[4][2];
        #pragma unroll
        for (int mf = 0; mf < 4; ++mf)
            #pragma unroll
            for (int nf = 0; nf < 2; ++nf) acc[mf][nf] = (f32x4){0.f,0.f,0.f,0.f};

        #pragma unroll
        for (int s = 0; s < 8; ++s) {
            int cbyte = s*64 + g*16;
            int r0 = l15, r1 = 16 + l15;
            short8 B0 = *reinterpret_cast<const short8*>(&tile[buf][r0 * DB + SWZ(r0, cbyte)]);
            short8 B1 = *reinterpret_cast<const short8*>(&tile[buf][r1 * DB + SWZ(r1, cbyte)]);
            #pragma unroll
            for (int mf = 0; mf < 4; ++mf) {
                acc[mf][0] = __builtin_amdgcn_mfma_f32_16x16x32_bf16(A[mf][s], B0, acc[mf][0], 0, 0, 0);
                acc[mf][1] = __builtin_amdgcn_mfma_f32_16x16x32_bf16(A[mf][s], B1, acc[mf][1], 0, 0, 0);
            }
        }

        int C0 = Cbase + c * CHUNK;
        #pragma unroll
        for (int nf = 0; nf < 2; ++nf) {
            int Ct = C0 + nf * 16;
            float colp = 0.f;                // per-lane partial col sum (col Ct+l15)
            #pragma unroll
            for (int mf = 0; mf < 4; ++mf) {
                int Rt = Rw + mf * 16;
                bool dg = isDiag && (Ct == Rt);
                if (dg) {
                    #pragma unroll
                    for (int r = 0; r < 4; ++r) {
                        float v = acc[mf][nf][r];        // exp2-domain
                        float e = fast_exp2(v);
                        int rl = g * 4 + r;
                        if (l15 == rl) e = 0.f;                       // diagonal
                        if (l15 == (rl ^ 1)) pos[Rt + rl] = v * INV_S2; // raw dot
                        rsum[mf][r] += e;
                    }
                } else {
                    #pragma unroll
                    for (int r = 0; r < 4; ++r) {
                        float e = fast_exp2(acc[mf][nf][r]);
                        rsum[mf][r] += e;
                        colp += e;
                    }
                }
            }
            if (!isDiag) {
                // reduce over the 4 lane-groups (same l15): mirror contribution
                colp += __shfl_xor(colp, 16);
                colp += __shfl_xor(colp, 32);
                if (g == 0) atomicAdd(&den[Ct + l15], colp);
            }
        }
        __builtin_amdgcn_sched_barrier(0);
        __builtin_amdgcn_s_barrier();        // readers done before next STAGE
        buf ^= 1;
    }

    // flush row sums: reduce across the 16 cols held per lane-group
    #pragma unroll
    for (int mf = 0; mf < 4; ++mf) {
        #pragma unroll
        for (int r = 0; r < 4; ++r) {
            float v = rsum[mf][r];
            v += __shfl_xor(v, 1); v += __shfl_xor(v, 2);
            v += __shfl_xor(v, 4); v += __shfl_xor(v, 8);
            if (l15 == 0) atomicAdd(&den[Rw + mf*16 + g*4 + r], v);
        }
    }

    // ---- last block computes the final loss ----
    __shared__ int  amLast;
    __shared__ float red[4];
    __threadfence();                         // den/pos visible device-wide
    __syncthreads();
    if (tid == 0) amLast = (atomicAdd(counter, 1) == NTILES - 1);
    __syncthreads();
    if (!amLast) return;
    __threadfence();                         // acquire

    float s = 0.f;
    for (int i = tid; i < N2; i += 256) {
        float d = __hip_atomic_load(&den[i], __ATOMIC_RELAXED, __HIP_MEMORY_SCOPE_AGENT);
        float p = __hip_atomic_load(&pos[i], __ATOMIC_RELAXED, __HIP_MEMORY_SCOPE_AGENT);
        s += logf(d + 1e-8f) - 2.f * p;
    }
    #pragma unroll
    for (int off = 1; off < 64; off <<= 1) s += __shfl_xor(s, off);
    if (lane == 0) red[w] = s;
    __syncthreads();
    if (tid == 0) {
        float t = 0.f;
        #pragma unroll
        for (int i = 0; i < 4; ++i) t += red[i];
        out[0] = t * (1.f / (float)N2);
    }
}

extern "C" void kernel_launch(void* const* d_in, const int* in_sizes, int n_in,
                              void* d_out, int out_size, void* d_ws, size_t ws_size,
                              hipStream_t stream) {
    const float* z1 = (const float*)d_in[0];
    const float* z2 = (const float*)d_in[1];
    char* ws = (char*)d_ws;
    unsigned short* Zb = (unsigned short*)ws;                       // 4 MB bf16 Z
    float* den = (float*)(ws + (size_t)N2 * DB);                    // 32 KB
    float* pos = (float*)(ws + (size_t)N2 * DB + (size_t)N2 * 4);   // 32 KB
    int* counter = (int*)(ws + (size_t)N2 * DB + (size_t)N2 * 8);

    knorm<<<N2 / 4, 256, 0, stream>>>(z1, z2, Zb, den, counter);
    kmain<<<NTILES, 256, 0, stream>>>(Zb, den, pos, counter, (float*)d_out);
}